// Round 1
// baseline (1470.587 us; speedup 1.0000x reference)
//
#include <hip/hip_runtime.h>
#include <math.h>

// ClusterGCN 3-layer inference, MI355X.
// Layout per layer: agg[c,:] = sum_{e:(r->c)} x[r,:]*deginv[c]  (+ self loop)
//                   y = relu(agg @ W_out + b + x @ W_root)
// Final: log_softmax over 64 cols (one wave per row-group).

constexpr int DK = 128;   // inner dim for all layers

__global__ void k_deg_init(float* __restrict__ deg, int n) {
    int i = blockIdx.x * blockDim.x + threadIdx.x;
    if (i < n) deg[i] = 1.0f;   // self loop counts 1
}

__global__ void k_deg_count(const int* __restrict__ col, float* __restrict__ deg, int e) {
    int i = blockIdx.x * blockDim.x + threadIdx.x;
    if (i < e) atomicAdd(&deg[col[i]], 1.0f);
}

__global__ void k_deg_inv(float* __restrict__ deg, int n) {
    int i = blockIdx.x * blockDim.x + threadIdx.x;
    if (i < n) deg[i] = 1.0f / deg[i];   // deg >= 1 always (self loop)
}

// agg[i,:] = x[i,:] * deginv[i]   (self-loop term; also zero-initializes agg)
__global__ void k_agg_init(const float4* __restrict__ x, const float* __restrict__ deginv,
                           float4* __restrict__ agg, int n4) {
    int idx = blockIdx.x * blockDim.x + threadIdx.x;
    if (idx < n4) {
        int node = idx >> 5;         // 32 float4 per 128-float row
        float w = deginv[node];
        float4 v = x[idx];
        v.x *= w; v.y *= w; v.z *= w; v.w *= w;
        agg[idx] = v;
    }
}

// one thread per (edge, feature): agg[c,j] += x[r,j] * deginv[c]
__global__ void k_scatter(const int* __restrict__ row, const int* __restrict__ col,
                          const float* __restrict__ deginv, const float* __restrict__ x,
                          float* __restrict__ agg, int e) {
    int idx = blockIdx.x * blockDim.x + threadIdx.x;   // e*128 < 2^31
    int eidx = idx >> 7;
    int j    = idx & 127;
    if (eidx < e) {
        int r = row[eidx];
        int c = col[eidx];
        float w = deginv[c];
        atomicAdd(&agg[c * DK + j], x[r * DK + j] * w);
    }
}

// y[i,:] = relu(agg[i,:] @ Wout + b + xin[i,:] @ Wroot), R rows per block,
// DOUT threads (thread j = output column j). In-place y==xin is safe:
// rows are staged to LDS before any global write.
template <int DOUT, int R>
__global__ void k_linear(const float* __restrict__ agg, const float* xin,
                         const float* __restrict__ Wout, const float* __restrict__ bvec,
                         const float* __restrict__ Wroot, float* y, int n) {
    __shared__ float sA[R][DK];
    __shared__ float sX[R][DK];
    const int tid  = threadIdx.x;
    const int row0 = blockIdx.x * R;
    const int rows_here = min(R, n - row0);

    const float4* aggv = (const float4*)(agg + (size_t)row0 * DK);
    const float4* xv   = (const float4*)(xin + (size_t)row0 * DK);
    float4* sAv = (float4*)&sA[0][0];
    float4* sXv = (float4*)&sX[0][0];
    const int validv = rows_here * (DK / 4);
    for (int t = tid; t < R * (DK / 4); t += DOUT) {
        if (t < validv) { sAv[t] = aggv[t]; sXv[t] = xv[t]; }
    }
    __syncthreads();

    float acc[R];
    const float bj = bvec[tid];
#pragma unroll
    for (int r = 0; r < R; ++r) acc[r] = bj;

    for (int k = 0; k < DK; ++k) {
        float wo = Wout[k * DOUT + tid];
        float wr = Wroot[k * DOUT + tid];
#pragma unroll
        for (int r = 0; r < R; ++r) acc[r] += sA[r][k] * wo + sX[r][k] * wr;
    }

    for (int r = 0; r < rows_here; ++r) {
        y[(size_t)(row0 + r) * DOUT + tid] = fmaxf(acc[r], 0.0f);
    }
}

// layer 3: DOUT=64 (one wave), fused relu + log_softmax across the 64 lanes.
template <int R>
__global__ void k_linear3(const float* __restrict__ agg, const float* __restrict__ xin,
                          const float* __restrict__ Wout, const float* __restrict__ bvec,
                          const float* __restrict__ Wroot, float* __restrict__ y, int n) {
    constexpr int DOUT = 64;
    __shared__ float sA[R][DK];
    __shared__ float sX[R][DK];
    const int tid  = threadIdx.x;
    const int row0 = blockIdx.x * R;
    const int rows_here = min(R, n - row0);

    const float4* aggv = (const float4*)(agg + (size_t)row0 * DK);
    const float4* xv   = (const float4*)(xin + (size_t)row0 * DK);
    float4* sAv = (float4*)&sA[0][0];
    float4* sXv = (float4*)&sX[0][0];
    const int validv = rows_here * (DK / 4);
    for (int t = tid; t < R * (DK / 4); t += DOUT) {
        if (t < validv) { sAv[t] = aggv[t]; sXv[t] = xv[t]; }
    }
    __syncthreads();

    float acc[R];
    const float bj = bvec[tid];
#pragma unroll
    for (int r = 0; r < R; ++r) acc[r] = bj;

    for (int k = 0; k < DK; ++k) {
        float wo = Wout[k * DOUT + tid];
        float wr = Wroot[k * DOUT + tid];
#pragma unroll
        for (int r = 0; r < R; ++r) acc[r] += sA[r][k] * wo + sX[r][k] * wr;
    }

    for (int r = 0; r < rows_here; ++r) {
        float v = fmaxf(acc[r], 0.0f);
        // wave-wide (64-lane) max
        float m = v;
        for (int off = 32; off > 0; off >>= 1) m = fmaxf(m, __shfl_xor(m, off));
        float ex = expf(v - m);
        float s = ex;
        for (int off = 32; off > 0; off >>= 1) s += __shfl_xor(s, off);
        y[(size_t)(row0 + r) * DOUT + tid] = v - m - logf(s);
    }
}

extern "C" void kernel_launch(void* const* d_in, const int* in_sizes, int n_in,
                              void* d_out, int out_size, void* d_ws, size_t ws_size,
                              hipStream_t stream) {
    const float* x   = (const float*)d_in[0];
    const int*   ei  = (const int*)d_in[1];
    const float* W1o = (const float*)d_in[2];
    const float* b1  = (const float*)d_in[3];
    const float* W1r = (const float*)d_in[4];
    const float* W2o = (const float*)d_in[5];
    const float* b2  = (const float*)d_in[6];
    const float* W2r = (const float*)d_in[7];
    const float* W3o = (const float*)d_in[8];
    const float* b3  = (const float*)d_in[9];
    const float* W3r = (const float*)d_in[10];

    const int N = in_sizes[0] / DK;   // 50000
    const int E = in_sizes[1] / 2;    // 800000
    const int* row = ei;              // edge_index[0]
    const int* col = ei + E;          // edge_index[1]

    float* deg  = (float*)d_ws;                               // N floats
    float* bufA = deg + ((N + 63) & ~63);                     // N*DK agg
    float* bufB = bufA + (size_t)N * DK;                      // N*DK hidden
    float* out  = (float*)d_out;                              // N*64

    const int B = 256;
    // --- degrees ---
    k_deg_init<<<(N + B - 1) / B, B, 0, stream>>>(deg, N);
    k_deg_count<<<(E + B - 1) / B, B, 0, stream>>>(col, deg, E);
    k_deg_inv<<<(N + B - 1) / B, B, 0, stream>>>(deg, N);

    const int n4 = N * (DK / 4);
    const int scatT = E * DK;

    // --- layer 1 ---
    k_agg_init<<<(n4 + B - 1) / B, B, 0, stream>>>((const float4*)x, deg, (float4*)bufA, n4);
    k_scatter<<<(scatT + B - 1) / B, B, 0, stream>>>(row, col, deg, x, bufA, E);
    k_linear<128, 8><<<(N + 7) / 8, 128, 0, stream>>>(bufA, x, W1o, b1, W1r, bufB, N);

    // --- layer 2 (in-place over bufB) ---
    k_agg_init<<<(n4 + B - 1) / B, B, 0, stream>>>((const float4*)bufB, deg, (float4*)bufA, n4);
    k_scatter<<<(scatT + B - 1) / B, B, 0, stream>>>(row, col, deg, bufB, bufA, E);
    k_linear<128, 8><<<(N + 7) / 8, 128, 0, stream>>>(bufA, bufB, W2o, b2, W2r, bufB, N);

    // --- layer 3 + log_softmax ---
    k_agg_init<<<(n4 + B - 1) / B, B, 0, stream>>>((const float4*)bufB, deg, (float4*)bufA, n4);
    k_scatter<<<(scatT + B - 1) / B, B, 0, stream>>>(row, col, deg, bufB, bufA, E);
    k_linear3<8><<<(N + 7) / 8, 64, 0, stream>>>(bufA, bufB, W3o, b3, W3r, out, N);
}

// Round 2
// 574.353 us; speedup vs baseline: 2.5604x; 2.5604x over previous
//
#include <hip/hip_runtime.h>
#include <math.h>

// ClusterGCN 3-layer inference, MI355X — CSR-gather formulation.
// Per call: build col-sorted CSR (histogram -> scan -> fill), then per layer
// one fused kernel: gather in-neighbors (no atomics) + dual-GEMM + ReLU.
// Self-loop folded into gather init; deginv = 1/(deg_in + 1).

constexpr int DK = 128;

__global__ void k_zero(int* __restrict__ p, int n) {
    int i = blockIdx.x * blockDim.x + threadIdx.x;
    if (i < n) p[i] = 0;
}

__global__ void k_hist(const int* __restrict__ col, int* __restrict__ degc, int e) {
    int i = blockIdx.x * blockDim.x + threadIdx.x;
    if (i < e) atomicAdd(&degc[col[i]], 1);
}

// Single-block exclusive scan over degc -> offs[0..n], rewrites degc as the
// fill cursor (same exclusive offsets), and emits deginv = 1/(deg+1).
// 1024 threads: wave-shfl scan + 16-wave combine; ~n/1024 chunks.
__global__ void k_scan(int* __restrict__ degc, int* __restrict__ offs,
                       float* __restrict__ deginv, int n) {
    __shared__ int wsum[16];
    __shared__ int s_carry;
    const int tid = threadIdx.x;
    const int lane = tid & 63, wid = tid >> 6;
    if (tid == 0) s_carry = 0;
    __syncthreads();
    for (int base = 0; base < n; base += 1024) {
        int i = base + tid;
        int orig = (i < n) ? degc[i] : 0;
        int v = orig;
#pragma unroll
        for (int off = 1; off < 64; off <<= 1) {
            int t = __shfl_up(v, off);
            if (lane >= off) v += t;
        }
        if (lane == 63) wsum[wid] = v;
        __syncthreads();
        if (wid == 0) {
            int wv = (lane < 16) ? wsum[lane] : 0;
#pragma unroll
            for (int off = 1; off < 16; off <<= 1) {
                int t = __shfl_up(wv, off);
                if (lane >= off) wv += t;
            }
            if (lane < 16) wsum[lane] = wv;
        }
        __syncthreads();
        int incl = v + ((wid > 0) ? wsum[wid - 1] : 0);
        int carry = s_carry;
        if (i < n) {
            int excl = carry + incl - orig;
            degc[i] = excl;           // becomes fill cursor
            offs[i] = excl;
            deginv[i] = 1.0f / (float)(orig + 1);
        }
        __syncthreads();
        if (tid == 1023) s_carry = carry + incl;
        __syncthreads();
    }
    if (tid == 0) offs[n] = s_carry;
}

__global__ void k_fill(const int* __restrict__ row, const int* __restrict__ col,
                       int* __restrict__ cursor, int* __restrict__ srow, int e) {
    int i = blockIdx.x * blockDim.x + threadIdx.x;
    if (i < e) {
        int c = col[i];
        int pos = atomicAdd(&cursor[c], 1);
        srow[pos] = row[i];
    }
}

// Fused layer: 8 nodes/block, 256 threads.
// Phase 1: half-wave (32 lanes, float4) per node gathers in-neighbor rows
//          (+self) into LDS; scaled copy -> sA, raw x row -> sX.
// Phase 2: dual GEMM from LDS: y = relu(sA@Wout + b + sX@Wroot).
template <int DOUT>
__global__ void k_layer(const float4* __restrict__ xv, const int* __restrict__ offs,
                        const int* __restrict__ srow, const float* __restrict__ deginv,
                        const float* __restrict__ Wout, const float* __restrict__ bvec,
                        const float* __restrict__ Wroot, float* __restrict__ y, int n) {
    __shared__ float sA[8][DK];
    __shared__ float sX[8][DK];
    const int tid = threadIdx.x;
    const int nl = tid >> 5, lane = tid & 31;
    const int node0 = blockIdx.x * 8;
    const int node = node0 + nl;

    if (node < n) {
        float4 self = xv[(size_t)node * 32 + lane];
        float4 acc = self;
        int s = offs[node], e = offs[node + 1];
        for (int i = s; i < e; ++i) {
            int r = srow[i];
            float4 v = xv[(size_t)r * 32 + lane];
            acc.x += v.x; acc.y += v.y; acc.z += v.z; acc.w += v.w;
        }
        float w = deginv[node];
        acc.x *= w; acc.y *= w; acc.z *= w; acc.w *= w;
        ((float4*)&sX[nl][0])[lane] = self;
        ((float4*)&sA[nl][0])[lane] = acc;
    }
    __syncthreads();

    const int j = tid & (DOUT - 1);
    const int rh = tid / DOUT;
    constexpr int RPT = 8 / (256 / DOUT);   // 128->4 rows/thread, 64->2
    float acc2[RPT];
    const float bj = bvec[j];
#pragma unroll
    for (int r = 0; r < RPT; ++r) acc2[r] = bj;

    for (int k = 0; k < DK; ++k) {
        float wo = Wout[k * DOUT + j];
        float wr = Wroot[k * DOUT + j];
#pragma unroll
        for (int r = 0; r < RPT; ++r) {
            int rr = rh * RPT + r;
            acc2[r] += sA[rr][k] * wo + sX[rr][k] * wr;
        }
    }
#pragma unroll
    for (int r = 0; r < RPT; ++r) {
        int rr = rh * RPT + r;
        if (node0 + rr < n)
            y[(size_t)(node0 + rr) * DOUT + j] = fmaxf(acc2[r], 0.0f);
    }
}

// Layer 3: DOUT=64, fused relu + log_softmax (64-lane wave reductions).
__global__ void k_layer3(const float4* __restrict__ xv, const int* __restrict__ offs,
                         const int* __restrict__ srow, const float* __restrict__ deginv,
                         const float* __restrict__ Wout, const float* __restrict__ bvec,
                         const float* __restrict__ Wroot, float* __restrict__ y, int n) {
    constexpr int DOUT = 64;
    __shared__ float sA[8][DK];
    __shared__ float sX[8][DK];
    const int tid = threadIdx.x;
    const int nl = tid >> 5, lane = tid & 31;
    const int node0 = blockIdx.x * 8;
    const int node = node0 + nl;

    if (node < n) {
        float4 self = xv[(size_t)node * 32 + lane];
        float4 acc = self;
        int s = offs[node], e = offs[node + 1];
        for (int i = s; i < e; ++i) {
            int r = srow[i];
            float4 v = xv[(size_t)r * 32 + lane];
            acc.x += v.x; acc.y += v.y; acc.z += v.z; acc.w += v.w;
        }
        float w = deginv[node];
        acc.x *= w; acc.y *= w; acc.z *= w; acc.w *= w;
        ((float4*)&sX[nl][0])[lane] = self;
        ((float4*)&sA[nl][0])[lane] = acc;
    }
    __syncthreads();

    const int j = tid & 63;
    const int rh = tid >> 6;            // wave id, rows 2*rh, 2*rh+1
    float acc2[2];
    const float bj = bvec[j];
    acc2[0] = bj; acc2[1] = bj;

    for (int k = 0; k < DK; ++k) {
        float wo = Wout[k * DOUT + j];
        float wr = Wroot[k * DOUT + j];
#pragma unroll
        for (int r = 0; r < 2; ++r) {
            int rr = rh * 2 + r;
            acc2[r] += sA[rr][k] * wo + sX[rr][k] * wr;
        }
    }
#pragma unroll
    for (int r = 0; r < 2; ++r) {
        int rr = rh * 2 + r;
        float v = fmaxf(acc2[r], 0.0f);
        float m = v;
        for (int off = 32; off > 0; off >>= 1) m = fmaxf(m, __shfl_xor(m, off));
        float ex = __expf(v - m);
        float s = ex;
        for (int off = 32; off > 0; off >>= 1) s += __shfl_xor(s, off);
        if (node0 + rr < n)
            y[(size_t)(node0 + rr) * DOUT + j] = v - m - __logf(s);
    }
}

extern "C" void kernel_launch(void* const* d_in, const int* in_sizes, int n_in,
                              void* d_out, int out_size, void* d_ws, size_t ws_size,
                              hipStream_t stream) {
    const float* x   = (const float*)d_in[0];
    const int*   ei  = (const int*)d_in[1];
    const float* W1o = (const float*)d_in[2];
    const float* b1  = (const float*)d_in[3];
    const float* W1r = (const float*)d_in[4];
    const float* W2o = (const float*)d_in[5];
    const float* b2  = (const float*)d_in[6];
    const float* W2r = (const float*)d_in[7];
    const float* W3o = (const float*)d_in[8];
    const float* b3  = (const float*)d_in[9];
    const float* W3r = (const float*)d_in[10];

    const int N = in_sizes[0] / DK;   // 50000
    const int E = in_sizes[1] / 2;    // 800000
    const int* row = ei;
    const int* col = ei + E;

    // workspace layout (4-byte units, 64-elt aligned blocks)
    int*   degc   = (int*)d_ws;                       // N (becomes cursor)
    int*   offs   = degc + ((N + 63) & ~63);          // N+1
    float* deginv = (float*)(offs + ((N + 64) & ~63));// N
    int*   srow   = (int*)(deginv + ((N + 63) & ~63));// E
    float* bufA   = (float*)(srow + ((E + 63) & ~63));// N*DK
    float* bufB   = bufA + (size_t)N * DK;            // N*DK
    float* out    = (float*)d_out;

    const int B = 256;
    k_zero<<<(N + B - 1) / B, B, 0, stream>>>(degc, N);
    k_hist<<<(E + B - 1) / B, B, 0, stream>>>(col, degc, E);
    k_scan<<<1, 1024, 0, stream>>>(degc, offs, deginv, N);
    k_fill<<<(E + B - 1) / B, B, 0, stream>>>(row, col, degc, srow, E);

    const int G = (N + 7) / 8;
    k_layer<128><<<G, 256, 0, stream>>>((const float4*)x,    offs, srow, deginv, W1o, b1, W1r, bufA, N);
    k_layer<128><<<G, 256, 0, stream>>>((const float4*)bufA, offs, srow, deginv, W2o, b2, W2r, bufB, N);
    k_layer3    <<<G, 256, 0, stream>>>((const float4*)bufB, offs, srow, deginv, W3o, b3, W3r, out, N);
}